// Round 3
// baseline (11478.064 us; speedup 1.0000x reference)
//
#include <hip/hip_runtime.h>

// ---------------------------------------------------------------------------
// DecoderLSTM: B=32, N=64, F=1280, H=512, E=512, V=10000, T=80, SOS=1
// Input dtype (f32 vs bf16) detected ON DEVICE; all kernels branch on the flag
// (wave-uniform, graph-safe). OUTPUT encoding follows the detected dtype:
// f32 inputs -> f32 outputs, bf16 inputs -> bf16 outputs. Output sub-regions
// addressed as ELEMENT offsets from d_out (element size resolved in-kernel).
// Internal compute f32, deterministic (no float atomics).
//   out layout (elements): logits[0, 25.6M) h[+16384] c[+16384] attn[+163840]
// ---------------------------------------------------------------------------

#define OFF_H    25600000ull
#define OFF_C    25616384ull
#define OFF_ATTN 25632768ull

struct __align__(8) U16x4 { unsigned short x, y, z, w; };
struct F4v { float x, y, z, w; };

static __device__ __forceinline__ float bf2f(unsigned short u) {
    return __uint_as_float(((unsigned)u) << 16);
}
static __device__ __forceinline__ unsigned short f2bf(float f) {
    unsigned u = __float_as_uint(f);
    u = (u + 0x7FFFu + ((u >> 16) & 1u)) >> 16;
    return (unsigned short)u;
}
static __device__ __forceinline__ float sigf(float x) { return 1.f / (1.f + expf(-x)); }

static __device__ __forceinline__ float toF(unsigned short u) { return bf2f(u); }
static __device__ __forceinline__ float toF(float f) { return f; }
static __device__ __forceinline__ F4v ld4(const unsigned short* p) {
    U16x4 v = *(const U16x4*)p;
    return { bf2f(v.x), bf2f(v.y), bf2f(v.z), bf2f(v.w) };
}
static __device__ __forceinline__ F4v ld4(const float* p) {
    float4 v = *(const float4*)p;
    return { v.x, v.y, v.z, v.w };
}

// output store at element index i (from d_out base); obf=1 -> bf16, 0 -> f32
static __device__ __forceinline__ void stw(void* o, size_t i, float v, int obf) {
    if (obf) ((unsigned short*)o)[i] = f2bf(v);
    else     ((float*)o)[i] = v;
}

// pack (value, index) so that u64 max() = argmax with first-index tie-break
static __device__ __forceinline__ unsigned long long packv(float v, int m) {
    unsigned u = __float_as_uint(v);
    u = (u & 0x80000000u) ? ~u : (u | 0x80000000u);
    return ((unsigned long long)u << 32) | (unsigned long long)(0xFFFFFFFFu - (unsigned)m);
}
static __device__ __forceinline__ unsigned long long shfl_xor_u64(unsigned long long v, int o) {
    unsigned hi = (unsigned)(v >> 32), lo = (unsigned)v;
    hi = __shfl_xor(hi, o); lo = __shfl_xor(lo, o);
    return ((unsigned long long)hi << 32) | lo;
}

struct Region {
    const void* W;      // [K][ldw]
    const void* W2;     // second weight for k>=512 (emb-gather region)
    const float* actT;  // f32 [K][32]
    float* part;        // f32 [KS][M][32]
    int M, KS, Kc, ldw, mode, nBlocks;   // mode: 0=plain, 1=emb-gather k>=512, 3=W rows +512
};
struct SkArgs { Region r[3]; int nReg; };

// ---- dtype detect + amax zero ----------------------------------------------
__global__ __launch_bounds__(256)
void detect_init(const unsigned short* __restrict__ featU, int* __restrict__ dtf,
                 unsigned long long* __restrict__ amax)
{
    if (threadIdx.x == 0) {
        int hits = 0;
        for (int i = 0; i < 128; ++i) {
            unsigned e = (featU[2 * i] >> 7) & 0xFF;   // even u16: mantissa-low if f32
            if (e >= 0x70 && e <= 0x8E) ++hits;
        }
        *dtf = (hits >= 64) ? 1 : 0;                   // 1 = bf16, 0 = f32
    }
    for (int i = threadIdx.x; i < 2560; i += 256) amax[i] = 0ull;
}

// ---- K1/K3: skinny GEMM, partial sums. Block: 128 m x 16 b, 256 thr. --------
template<typename T>
static __device__ __forceinline__
void skgemm_body(const SkArgs& a, int step, const unsigned long long* __restrict__ amax,
                 const T* __restrict__ emb)
{
    int local = blockIdx.x;
    Region R = a.r[0];
    if (a.nReg > 1 && local >= R.nBlocks) {
        local -= R.nBlocks; R = a.r[1];
        if (a.nReg > 2 && local >= R.nBlocks) { local -= R.nBlocks; R = a.r[2]; }
    }
    const int kc    = local % R.KS;
    const int rr    = local / R.KS;
    const int bHalf = rr & 1;
    const int mb    = rr >> 1;
    const int tid = threadIdx.x;
    const int tm = tid & 31, bg = tid >> 5;
    const int m0 = mb * 128 + tm * 4;
    const int b0 = bHalf * 16 + bg * 2;
    const int k0 = kc * R.Kc;
    const int rowOff = (R.mode == 3) ? 512 : 0;

    float a00=0.f,a01=0.f,a10=0.f,a11=0.f,a20=0.f,a21=0.f,a30=0.f,a31=0.f;

    const bool gather = (R.mode == 1) && (k0 >= 512);
    const T* wp = (gather ? ((const T*)R.W2 + (size_t)(k0 - 512) * R.ldw)
                          : ((const T*)R.W  + (size_t)(k0 + rowOff) * R.ldw)) + m0;
    if (!gather) {
        const float* ap = R.actT + (size_t)k0 * 32 + b0;
        #pragma unroll 4
        for (int k = 0; k < R.Kc; ++k) {
            float2 av = *(const float2*)ap;
            F4v w = ld4(wp);
            a00 += w.x * av.x; a01 += w.x * av.y;
            a10 += w.y * av.x; a11 += w.y * av.y;
            a20 += w.z * av.x; a21 += w.z * av.y;
            a30 += w.w * av.x; a31 += w.w * av.y;
            ap += 32; wp += R.ldw;
        }
    } else {
        int idx0 = 1, idx1 = 1;  // SOS at t=0
        if (step > 0) {
            unsigned long long p0 = amax[(step - 1) * 32 + b0];
            unsigned long long p1 = amax[(step - 1) * 32 + b0 + 1];
            idx0 = (int)(0xFFFFFFFFu - (unsigned)(p0 & 0xFFFFFFFFull));
            idx1 = (int)(0xFFFFFFFFu - (unsigned)(p1 & 0xFFFFFFFFull));
            idx0 &= 0x3FFF; if (idx0 > 9999) idx0 = 9999;   // OOB guard
            idx1 &= 0x3FFF; if (idx1 > 9999) idx1 = 9999;
        }
        const T* e0 = emb + (size_t)idx0 * 512 + (k0 - 512);
        const T* e1 = emb + (size_t)idx1 * 512 + (k0 - 512);
        #pragma unroll 4
        for (int k = 0; k < R.Kc; ++k) {
            float ax = toF(e0[k]), ay = toF(e1[k]);
            F4v w = ld4(wp);
            a00 += w.x * ax; a01 += w.x * ay;
            a10 += w.y * ax; a11 += w.y * ay;
            a20 += w.z * ax; a21 += w.z * ay;
            a30 += w.w * ax; a31 += w.w * ay;
            wp += R.ldw;
        }
    }
    float* pp = R.part + ((size_t)kc * R.M + m0) * 32 + b0;
    *(float2*)(pp)      = make_float2(a00, a01);
    *(float2*)(pp + 32) = make_float2(a10, a11);
    *(float2*)(pp + 64) = make_float2(a20, a21);
    *(float2*)(pp + 96) = make_float2(a30, a31);
}

__global__ __launch_bounds__(256)
void skgemm(SkArgs a, int step, const unsigned long long* __restrict__ amax,
            const void* __restrict__ emb, const int* __restrict__ dtf)
{
    if (*dtf) skgemm_body<unsigned short>(a, step, amax, (const unsigned short*)emb);
    else      skgemm_body<float>(a, step, amax, (const float*)emb);
}

// ---- K2: attention, one block per batch row --------------------------------
template<typename T>
static __device__ __forceinline__
void attn_body(const float* __restrict__ hq_part, const float* __restrict__ gate_part,
               const float* __restrict__ encT, const T* __restrict__ feat,
               const T* __restrict__ b1, const T* __restrict__ Va,
               const T* __restrict__ bVa, const T* __restrict__ bg_,
               float* __restrict__ ctxgT, void* __restrict__ dout, int step, int obf)
{
    __shared__ float hqL[512], VaL[512], wL[64], sred[4][64];
    const int b = blockIdx.x, tid = threadIdx.x;
    for (int j = tid; j < 512; j += 256) {
        hqL[j] = hq_part[j * 32 + b] + hq_part[(512 + j) * 32 + b] + toF(b1[j]);
        VaL[j] = toF(Va[j]);
    }
    __syncthreads();
    {   // scores: 64 n's per wave -> coalesced encT reads
        const int n = tid & 63, jq = tid >> 6;
        float s = 0.f;
        const float* ep = encT + (size_t)b * 32768 + n;
        for (int jj = 0; jj < 128; ++jj) {
            int j = jq * 128 + jj;
            float v = hqL[j] + ep[(size_t)j * 64];
            s += fmaxf(v, 0.f) * VaL[j];
        }
        sred[jq][n] = s;
    }
    __syncthreads();
    if (tid < 64) {
        float s = sred[0][tid] + sred[1][tid] + sred[2][tid] + sred[3][tid] + toF(bVa[0]);
        float mx = s;
        for (int o = 32; o; o >>= 1) mx = fmaxf(mx, __shfl_xor(mx, o));
        float e = expf(s - mx);
        float sum = e;
        for (int o = 32; o; o >>= 1) sum += __shfl_xor(sum, o);
        float w = e / sum;
        wL[tid] = w;
        stw(dout, OFF_ATTN + ((size_t)b * 80 + step) * 64 + tid, w, obf);
    }
    __syncthreads();
    float ctx[5] = {0.f, 0.f, 0.f, 0.f, 0.f};
    const T* fp = feat + (size_t)b * 64 * 1280;
    for (int nn = 0; nn < 64; ++nn) {
        float wn = wL[nn];
        const T* fr = fp + (size_t)nn * 1280 + tid;
        #pragma unroll
        for (int i = 0; i < 5; ++i) ctx[i] += wn * toF(fr[i * 256]);
    }
    #pragma unroll
    for (int i = 0; i < 5; ++i) {
        int f = tid + i * 256;
        float g = gate_part[f * 32 + b] + gate_part[(1280 + f) * 32 + b] + toF(bg_[f]);
        g = 1.f / (1.f + expf(-g));
        ctxgT[f * 32 + b] = ctx[i] * g;
    }
}

__global__ __launch_bounds__(256)
void attn_kernel(const float* hq_part, const float* gate_part, const float* encT,
                 const void* feat, const void* b1, const void* Va, const void* bVa,
                 const void* bg_, float* ctxgT, void* dout, int step,
                 const int* __restrict__ dtf)
{
    int f = *dtf;
    if (f) attn_body<unsigned short>(hq_part, gate_part, encT,
               (const unsigned short*)feat, (const unsigned short*)b1,
               (const unsigned short*)Va, (const unsigned short*)bVa,
               (const unsigned short*)bg_, ctxgT, dout, step, f);
    else   attn_body<float>(hq_part, gate_part, encT,
               (const float*)feat, (const float*)b1, (const float*)Va,
               (const float*)bVa, (const float*)bg_, ctxgT, dout, step, f);
}

// ---- K3b: LSTM pointwise ----------------------------------------------------
template<typename T>
static __device__ __forceinline__
void lstm_body(const float* __restrict__ gates_part, const T* __restrict__ blstm,
               float* __restrict__ cT, float* __restrict__ actT_h,
               void* __restrict__ dout, int step, int obf)
{
    int g = blockIdx.x * 256 + threadIdx.x;   // 16384 = 512*32
    int b = g & 31, j = g >> 5;
    float gi = toF(blstm[j]),        gf = toF(blstm[j + 512]);
    float gg = toF(blstm[j + 1024]), go = toF(blstm[j + 1536]);
    #pragma unroll
    for (int kc = 0; kc < 8; ++kc) {
        const float* p = gates_part + (size_t)kc * 2048 * 32;
        gi += p[(j       ) * 32 + b];
        gf += p[(j +  512) * 32 + b];
        gg += p[(j + 1024) * 32 + b];
        go += p[(j + 1536) * 32 + b];
    }
    float c  = cT[j * 32 + b];
    float c2 = sigf(gf) * c + sigf(gi) * tanhf(gg);
    float h2 = sigf(go) * tanhf(c2);
    cT[j * 32 + b] = c2;
    actT_h[j * 32 + b] = h2;
    if (step == 79) {
        stw(dout, OFF_H + (size_t)b * 512 + j, h2, obf);
        stw(dout, OFF_C + (size_t)b * 512 + j, c2, obf);
    }
}

__global__ __launch_bounds__(256)
void lstm_pw(const float* gates_part, const void* blstm, float* cT, float* actT_h,
             void* dout, int step, const int* __restrict__ dtf)
{
    int f = *dtf;
    if (f) lstm_body<unsigned short>(gates_part, (const unsigned short*)blstm,
                                     cT, actT_h, dout, step, f);
    else   lstm_body<float>(gates_part, (const float*)blstm, cT, actT_h, dout, step, f);
}

// ---- K4: logits + store + argmax --------------------------------------------
template<typename T>
static __device__ __forceinline__
void logits_body(const float* __restrict__ actT_h, const T* __restrict__ Wout,
                 const T* __restrict__ bout, void* __restrict__ dout,
                 unsigned long long* __restrict__ amax, int step, int obf)
{
    const int mb = blockIdx.x >> 1, bHalf = blockIdx.x & 1;
    const int tid = threadIdx.x, tm = tid & 31, bg = tid >> 5;
    const int m0 = mb * 128 + tm * 4;
    const int m0c = (m0 <= 9996) ? m0 : 9996;
    const int b0 = bHalf * 16 + bg * 2;

    float a00=0.f,a01=0.f,a10=0.f,a11=0.f,a20=0.f,a21=0.f,a30=0.f,a31=0.f;
    const float* ap = actT_h + b0;
    const T* wp = Wout + m0c;
    #pragma unroll 4
    for (int k = 0; k < 512; ++k) {
        float2 av = *(const float2*)ap;
        F4v w = ld4(wp);
        a00 += w.x * av.x; a01 += w.x * av.y;
        a10 += w.y * av.x; a11 += w.y * av.y;
        a20 += w.z * av.x; a21 += w.z * av.y;
        a30 += w.w * av.x; a31 += w.w * av.y;
        ap += 32; wp += 10000;
    }
    unsigned long long best0 = 0ull, best1 = 0ull;
    if (m0 <= 9996) {
        float bb0 = toF(bout[m0]),     bb1 = toF(bout[m0 + 1]);
        float bb2 = toF(bout[m0 + 2]), bb3 = toF(bout[m0 + 3]);
        float l00 = a00 + bb0, l10 = a10 + bb1, l20 = a20 + bb2, l30 = a30 + bb3;
        float l01 = a01 + bb0, l11 = a11 + bb1, l21 = a21 + bb2, l31 = a31 + bb3;
        size_t o0 = ((size_t)(b0    ) * 80 + step) * 10000 + m0;
        size_t o1 = ((size_t)(b0 + 1) * 80 + step) * 10000 + m0;
        if (obf) {
            U16x4 s0 = { f2bf(l00), f2bf(l10), f2bf(l20), f2bf(l30) };
            U16x4 s1 = { f2bf(l01), f2bf(l11), f2bf(l21), f2bf(l31) };
            *(U16x4*)((unsigned short*)dout + o0) = s0;
            *(U16x4*)((unsigned short*)dout + o1) = s1;
        } else {
            *(float4*)((float*)dout + o0) = make_float4(l00, l10, l20, l30);
            *(float4*)((float*)dout + o1) = make_float4(l01, l11, l21, l31);
        }
        best0 = packv(l00, m0);
        unsigned long long p;
        p = packv(l10, m0+1); if (p > best0) best0 = p;
        p = packv(l20, m0+2); if (p > best0) best0 = p;
        p = packv(l30, m0+3); if (p > best0) best0 = p;
        best1 = packv(l01, m0);
        p = packv(l11, m0+1); if (p > best1) best1 = p;
        p = packv(l21, m0+2); if (p > best1) best1 = p;
        p = packv(l31, m0+3); if (p > best1) best1 = p;
    }
    #pragma unroll
    for (int o = 16; o; o >>= 1) {
        unsigned long long v0 = shfl_xor_u64(best0, o);
        unsigned long long v1 = shfl_xor_u64(best1, o);
        if (v0 > best0) best0 = v0;
        if (v1 > best1) best1 = v1;
    }
    if (tm == 0) {
        atomicMax(&amax[step * 32 + b0],     best0);
        atomicMax(&amax[step * 32 + b0 + 1], best1);
    }
}

__global__ __launch_bounds__(256)
void logits_kernel(const float* actT_h, const void* Wout, const void* bout,
                   void* dout, unsigned long long* amax, int step,
                   const int* __restrict__ dtf)
{
    int f = *dtf;
    if (f) logits_body<unsigned short>(actT_h, (const unsigned short*)Wout,
                                       (const unsigned short*)bout, dout, amax, step, f);
    else   logits_body<float>(actT_h, (const float*)Wout, (const float*)bout,
                              dout, amax, step, f);
}

// ---- init kernels -----------------------------------------------------------
template<typename T>
static __device__ __forceinline__
void mean_body(const T* __restrict__ feat, float* __restrict__ meanT)
{
    int e = blockIdx.x * 256 + threadIdx.x;    // 40960 = 32*1280
    int f = e % 1280, b = e / 1280;
    const T* p = feat + (size_t)b * 64 * 1280 + f;
    float s = 0.f;
    for (int nn = 0; nn < 64; ++nn) s += toF(p[(size_t)nn * 1280]);
    meanT[f * 32 + b] = s * (1.f / 64.f);
}
__global__ __launch_bounds__(256)
void init_mean(const void* feat, float* meanT, const int* __restrict__ dtf)
{
    if (*dtf) mean_body<unsigned short>((const unsigned short*)feat, meanT);
    else      mean_body<float>((const float*)feat, meanT);
}

template<typename T>
static __device__ __forceinline__
void inithc_body(const float* __restrict__ meanT, const T* __restrict__ Wh,
                 const T* __restrict__ bh, const T* __restrict__ Wc,
                 const T* __restrict__ bc, float* __restrict__ actT_h, float* __restrict__ cT)
{
    int mb = blockIdx.x >> 2, bq = blockIdx.x & 3;
    int tid = threadIdx.x, tm = tid & 31;
    int m0 = mb * 128 + tm * 4;
    int b = bq * 8 + (tid >> 5);
    bool isH = (m0 < 512);
    const T* W = isH ? Wh : Wc;
    int mw = isH ? m0 : (m0 - 512);
    float a0=0.f,a1=0.f,a2=0.f,a3=0.f;
    const float* ap = meanT + b;
    const T* wp = W + mw;
    #pragma unroll 4
    for (int k = 0; k < 1280; ++k) {
        float av = *ap;
        F4v w = ld4(wp);
        a0 += w.x * av; a1 += w.y * av; a2 += w.z * av; a3 += w.w * av;
        ap += 32; wp += 512;
    }
    const T* bias = isH ? bh : bc;
    float* dst = isH ? actT_h : cT;
    dst[(mw + 0) * 32 + b] = a0 + toF(bias[mw + 0]);
    dst[(mw + 1) * 32 + b] = a1 + toF(bias[mw + 1]);
    dst[(mw + 2) * 32 + b] = a2 + toF(bias[mw + 2]);
    dst[(mw + 3) * 32 + b] = a3 + toF(bias[mw + 3]);
}
__global__ __launch_bounds__(256)
void init_hc(const float* meanT, const void* Wh, const void* bh, const void* Wc,
             const void* bc, float* actT_h, float* cT, const int* __restrict__ dtf)
{
    if (*dtf) inithc_body<unsigned short>(meanT, (const unsigned short*)Wh,
                  (const unsigned short*)bh, (const unsigned short*)Wc,
                  (const unsigned short*)bc, actT_h, cT);
    else      inithc_body<float>(meanT, (const float*)Wh, (const float*)bh,
                  (const float*)Wc, (const float*)bc, actT_h, cT);
}

// enc_projT[b][j][n] = (feat @ W2 + b2), transposed for coalesced attention reads
template<typename T>
static __device__ __forceinline__
void encproj_body(const T* __restrict__ feat, const T* __restrict__ W2,
                  const T* __restrict__ b2, float* __restrict__ encT)
{
    int jb = blockIdx.x & 3, rowb = blockIdx.x >> 2;
    int tid = threadIdx.x, tm = tid & 31, bg = tid >> 5;
    int j0 = jb * 128 + tm * 4;
    int r0 = rowb * 16 + bg * 2;
    float a00=0.f,a01=0.f,a10=0.f,a11=0.f,a20=0.f,a21=0.f,a30=0.f,a31=0.f;
    const T* f0 = feat + (size_t)r0 * 1280;
    const T* f1 = f0 + 1280;
    const T* wp = W2 + j0;
    #pragma unroll 4
    for (int k = 0; k < 1280; ++k) {
        float ax = toF(f0[k]), ay = toF(f1[k]);
        F4v w = ld4(wp);
        a00 += w.x * ax; a01 += w.x * ay;
        a10 += w.y * ax; a11 += w.y * ay;
        a20 += w.z * ax; a21 += w.z * ay;
        a30 += w.w * ax; a31 += w.w * ay;
        wp += 512;
    }
    int b = r0 >> 6, n = r0 & 63;
    float* base = encT + (size_t)b * 32768 + n;
    float bb;
    bb = toF(b2[j0 + 0]); *(float2*)(base + (size_t)(j0 + 0) * 64) = make_float2(a00 + bb, a01 + bb);
    bb = toF(b2[j0 + 1]); *(float2*)(base + (size_t)(j0 + 1) * 64) = make_float2(a10 + bb, a11 + bb);
    bb = toF(b2[j0 + 2]); *(float2*)(base + (size_t)(j0 + 2) * 64) = make_float2(a20 + bb, a21 + bb);
    bb = toF(b2[j0 + 3]); *(float2*)(base + (size_t)(j0 + 3) * 64) = make_float2(a30 + bb, a31 + bb);
}
__global__ __launch_bounds__(256)
void encproj(const void* feat, const void* W2, const void* b2, float* encT,
             const int* __restrict__ dtf)
{
    if (*dtf) encproj_body<unsigned short>((const unsigned short*)feat,
                  (const unsigned short*)W2, (const unsigned short*)b2, encT);
    else      encproj_body<float>((const float*)feat, (const float*)W2,
                  (const float*)b2, encT);
}

// ---------------------------------------------------------------------------
extern "C" void kernel_launch(void* const* d_in, const int* in_sizes, int n_in,
                              void* d_out, int out_size, void* d_ws, size_t ws_size,
                              hipStream_t stream)
{
    (void)in_sizes; (void)n_in; (void)out_size; (void)ws_size;

    const void* feat  = d_in[0];
    // d_in[1] caption (unused), d_in[2] max_caption (=80, hardcoded)
    const void* emb   = d_in[3];
    const void* W1    = d_in[4];
    const void* b1    = d_in[5];
    const void* W2    = d_in[6];
    const void* b2    = d_in[7];
    const void* Va    = d_in[8];
    const void* bVa   = d_in[9];
    const void* Wh    = d_in[10];
    const void* bh    = d_in[11];
    const void* Wc    = d_in[12];
    const void* bc    = d_in[13];
    const void* Wg    = d_in[14];
    const void* bg    = d_in[15];
    const void* Wx    = d_in[16];
    const void* Whh   = d_in[17];
    const void* blstm = d_in[18];
    const void* Wout  = d_in[19];
    const void* bout  = d_in[20];

    float* ws         = (float*)d_ws;
    float* encT       = ws;                    // 1,048,576
    float* meanT      = encT + 1048576;        // 40,960
    float* actT_h     = meanT + 40960;         // 16,384
    float* cT         = actT_h + 16384;        // 16,384
    float* hq_part    = cT + 16384;            // 2*512*32
    float* gate_part  = hq_part + 32768;       // 2*1280*32
    float* gates_part = gate_part + 81920;     // 8*2048*32
    float* ctxgT      = gates_part + 524288;   // 40,960
    unsigned long long* amax = (unsigned long long*)(ctxgT + 40960);  // 80*32 u64
    int* dtf          = (int*)(amax + 2560);

    detect_init<<<1, 256, 0, stream>>>((const unsigned short*)feat, dtf, amax);
    init_mean<<<160, 256, 0, stream>>>(feat, meanT, dtf);
    init_hc  <<<32, 256, 0, stream>>>(meanT, Wh, bh, Wc, bc, actT_h, cT, dtf);
    encproj  <<<512, 256, 0, stream>>>(feat, W2, b2, encT, dtf);

    // Region: W, W2, actT, part, M, KS, Kc, ldw, mode, nBlocks
    SkArgs k1{};
    k1.r[0] = { W1,  nullptr, actT_h, hq_part,    512, 2, 256,  512, 0,  16 };
    k1.r[1] = { Wg,  nullptr, actT_h, gate_part, 1280, 2, 256, 1280, 0,  40 };
    k1.r[2] = { Whh, Wx,      actT_h, gates_part,2048, 4, 256, 2048, 1, 128 };
    k1.nReg = 3;
    SkArgs k3{};
    k3.r[0] = { Wx, nullptr, ctxgT,
                gates_part + (size_t)4 * 2048 * 32, 2048, 4, 320, 2048, 3, 128 };
    k3.nReg = 1;

    for (int t = 0; t < 80; ++t) {
        skgemm       <<<184, 256, 0, stream>>>(k1, t, amax, emb, dtf);
        attn_kernel  <<<32,  256, 0, stream>>>(hq_part, gate_part, encT, feat,
                                               b1, Va, bVa, bg, ctxgT, d_out, t, dtf);
        skgemm       <<<128, 256, 0, stream>>>(k3, t, amax, emb, dtf);
        lstm_pw      <<<64,  256, 0, stream>>>(gates_part, blstm, cT, actT_h, d_out, t, dtf);
        logits_kernel<<<158, 256, 0, stream>>>(actT_h, Wout, bout, d_out, amax, t, dtf);
    }
}

// Round 4
// 8487.680 us; speedup vs baseline: 1.3523x; 1.3523x over previous
//
#include <hip/hip_runtime.h>

// ---------------------------------------------------------------------------
// DecoderLSTM: B=32, N=64, F=1280, H=512, E=512, V=10000, T=80, SOS=1
// R4: latency-bound fix — K-split all GEMMs (320-632 blocks/dispatch, 128
// k-iters/thread, unroll 8), logits GEMM k-split + finalize kernel, attention
// with 1024-thread blocks. Input dtype (f32 vs bf16) detected on device;
// output encoding follows input dtype. Internal f32, deterministic.
//   out layout (elements): logits[0,25.6M) h[+16384] c[+16384] attn[+163840]
// ---------------------------------------------------------------------------

#define OFF_H    25600000ull
#define OFF_C    25616384ull
#define OFF_ATTN 25632768ull

struct __align__(8) U16x4 { unsigned short x, y, z, w; };
struct F4v { float x, y, z, w; };

static __device__ __forceinline__ float bf2f(unsigned short u) {
    return __uint_as_float(((unsigned)u) << 16);
}
static __device__ __forceinline__ unsigned short f2bf(float f) {
    unsigned u = __float_as_uint(f);
    u = (u + 0x7FFFu + ((u >> 16) & 1u)) >> 16;
    return (unsigned short)u;
}
static __device__ __forceinline__ float sigf(float x) { return 1.f / (1.f + expf(-x)); }

static __device__ __forceinline__ float toF(unsigned short u) { return bf2f(u); }
static __device__ __forceinline__ float toF(float f) { return f; }
static __device__ __forceinline__ F4v ld4(const unsigned short* p) {
    U16x4 v = *(const U16x4*)p;
    return { bf2f(v.x), bf2f(v.y), bf2f(v.z), bf2f(v.w) };
}
static __device__ __forceinline__ F4v ld4(const float* p) {
    float4 v = *(const float4*)p;
    return { v.x, v.y, v.z, v.w };
}

// output store at element index i (from d_out base); obf=1 -> bf16, 0 -> f32
static __device__ __forceinline__ void stw(void* o, size_t i, float v, int obf) {
    if (obf) ((unsigned short*)o)[i] = f2bf(v);
    else     ((float*)o)[i] = v;
}

// pack (value, index) so that u64 max() = argmax with first-index tie-break
static __device__ __forceinline__ unsigned long long packv(float v, int m) {
    unsigned u = __float_as_uint(v);
    u = (u & 0x80000000u) ? ~u : (u | 0x80000000u);
    return ((unsigned long long)u << 32) | (unsigned long long)(0xFFFFFFFFu - (unsigned)m);
}
static __device__ __forceinline__ unsigned long long shfl_xor_u64(unsigned long long v, int o) {
    unsigned hi = (unsigned)(v >> 32), lo = (unsigned)v;
    hi = __shfl_xor(hi, o); lo = __shfl_xor(lo, o);
    return ((unsigned long long)hi << 32) | lo;
}

struct Region {
    const void* W;      // [K][ldw]
    const void* W2;     // second weight for k>=512 (emb-gather region, mode 1)
    const float* actT;  // f32 [K][32]
    float* part;        // f32 [KS][M][32]
    int M, KS, Kc, ldw, mode, nBlocks;   // mode: 0=plain, 1=emb-gather k>=512, 3=W rows +512
};
struct SkArgs { Region r[3]; int nReg; };

// ---- dtype detect + amax zero ----------------------------------------------
__global__ __launch_bounds__(256)
void detect_init(const unsigned short* __restrict__ featU, int* __restrict__ dtf,
                 unsigned long long* __restrict__ amax)
{
    if (threadIdx.x == 0) {
        int hits = 0;
        for (int i = 0; i < 128; ++i) {
            unsigned e = (featU[2 * i] >> 7) & 0xFF;   // even u16: mantissa-low if f32
            if (e >= 0x70 && e <= 0x8E) ++hits;
        }
        *dtf = (hits >= 64) ? 1 : 0;                   // 1 = bf16, 0 = f32
    }
    for (int i = threadIdx.x; i < 2560; i += 256) amax[i] = 0ull;
}

// ---- skinny GEMM, K-split partial sums. Block: 128 m x 16 b, 256 thr. -------
// Thread: 4 m x 2 b, Kc k-iterations, unroll 8 for load ILP.
template<typename T>
static __device__ __forceinline__
void skgemm_body(const SkArgs& a, int step, const unsigned long long* __restrict__ amax,
                 const T* __restrict__ emb)
{
    int local = blockIdx.x;
    Region R = a.r[0];
    if (a.nReg > 1 && local >= R.nBlocks) {
        local -= R.nBlocks; R = a.r[1];
        if (a.nReg > 2 && local >= R.nBlocks) { local -= R.nBlocks; R = a.r[2]; }
    }
    const int kc    = local % R.KS;
    const int rr    = local / R.KS;
    const int bHalf = rr & 1;
    const int mb    = rr >> 1;
    const int tid = threadIdx.x;
    const int tm = tid & 31, bg = tid >> 5;
    int m0 = mb * 128 + tm * 4;
    if (m0 > R.M - 4) m0 = R.M - 4;          // clamp (V=10000 tail); dup writes benign
    const int b0 = bHalf * 16 + bg * 2;
    const int k0 = kc * R.Kc;
    const int rowOff = (R.mode == 3) ? 512 : 0;

    float a00=0.f,a01=0.f,a10=0.f,a11=0.f,a20=0.f,a21=0.f,a30=0.f,a31=0.f;

    const bool gather = (R.mode == 1) && (k0 >= 512);
    const T* wp = (gather ? ((const T*)R.W2 + (size_t)(k0 - 512) * R.ldw)
                          : ((const T*)R.W  + (size_t)(k0 + rowOff) * R.ldw)) + m0;
    if (!gather) {
        const float* ap = R.actT + (size_t)k0 * 32 + b0;
        #pragma unroll 8
        for (int k = 0; k < R.Kc; ++k) {
            float2 av = *(const float2*)ap;
            F4v w = ld4(wp);
            a00 += w.x * av.x; a01 += w.x * av.y;
            a10 += w.y * av.x; a11 += w.y * av.y;
            a20 += w.z * av.x; a21 += w.z * av.y;
            a30 += w.w * av.x; a31 += w.w * av.y;
            ap += 32; wp += R.ldw;
        }
    } else {
        int idx0 = 1, idx1 = 1;  // SOS at t=0
        if (step > 0) {
            unsigned long long p0 = amax[(step - 1) * 32 + b0];
            unsigned long long p1 = amax[(step - 1) * 32 + b0 + 1];
            idx0 = (int)(0xFFFFFFFFu - (unsigned)(p0 & 0xFFFFFFFFull));
            idx1 = (int)(0xFFFFFFFFu - (unsigned)(p1 & 0xFFFFFFFFull));
            idx0 &= 0x3FFF; if (idx0 > 9999) idx0 = 9999;   // OOB guard
            idx1 &= 0x3FFF; if (idx1 > 9999) idx1 = 9999;
        }
        const T* e0 = emb + (size_t)idx0 * 512 + (k0 - 512);
        const T* e1 = emb + (size_t)idx1 * 512 + (k0 - 512);
        #pragma unroll 8
        for (int k = 0; k < R.Kc; ++k) {
            float ax = toF(e0[k]), ay = toF(e1[k]);
            F4v w = ld4(wp);
            a00 += w.x * ax; a01 += w.x * ay;
            a10 += w.y * ax; a11 += w.y * ay;
            a20 += w.z * ax; a21 += w.z * ay;
            a30 += w.w * ax; a31 += w.w * ay;
            wp += R.ldw;
        }
    }
    float* pp = R.part + ((size_t)kc * R.M + m0) * 32 + b0;
    *(float2*)(pp)      = make_float2(a00, a01);
    *(float2*)(pp + 32) = make_float2(a10, a11);
    *(float2*)(pp + 64) = make_float2(a20, a21);
    *(float2*)(pp + 96) = make_float2(a30, a31);
}

__global__ __launch_bounds__(256)
void skgemm(SkArgs a, int step, const unsigned long long* __restrict__ amax,
            const void* __restrict__ emb, const int* __restrict__ dtf)
{
    if (*dtf) skgemm_body<unsigned short>(a, step, amax, (const unsigned short*)emb);
    else      skgemm_body<float>(a, step, amax, (const float*)emb);
}

// ---- attention: one block (1024 thr, 16 waves) per batch row ----------------
template<typename T>
static __device__ __forceinline__
void attn_body(const float* __restrict__ hq_part, const float* __restrict__ gate_part,
               const float* __restrict__ encT, const T* __restrict__ feat,
               const T* __restrict__ b1, const T* __restrict__ Va,
               const T* __restrict__ bVa, const T* __restrict__ bg_,
               float* __restrict__ ctxgT, void* __restrict__ dout, int step, int obf)
{
    __shared__ float hqL[512], VaL[512], wL[64], sred[16][64];
    const int b = blockIdx.x, tid = threadIdx.x;
    if (tid < 512) {
        float s = toF(b1[tid]);
        #pragma unroll
        for (int kp = 0; kp < 4; ++kp) s += hq_part[kp * 16384 + tid * 32 + b];
        hqL[tid] = s;
        VaL[tid] = toF(Va[tid]);
    }
    __syncthreads();
    {   // scores: 64 n's per wave-half; 16 jq groups of 32 j
        const int n = tid & 63, jq = tid >> 6;
        float s = 0.f;
        const float* ep = encT + (size_t)b * 32768 + n;
        #pragma unroll 8
        for (int jj = 0; jj < 32; ++jj) {
            int j = jq * 32 + jj;
            float v = hqL[j] + ep[(size_t)j * 64];
            s += fmaxf(v, 0.f) * VaL[j];
        }
        sred[jq][n] = s;
    }
    __syncthreads();
    if (tid < 64) {
        float s = toF(bVa[0]);
        #pragma unroll
        for (int q = 0; q < 16; ++q) s += sred[q][tid];
        float mx = s;
        for (int o = 32; o; o >>= 1) mx = fmaxf(mx, __shfl_xor(mx, o));
        float e = expf(s - mx);
        float sum = e;
        for (int o = 32; o; o >>= 1) sum += __shfl_xor(sum, o);
        float w = e / sum;
        wL[tid] = w;
        stw(dout, OFF_ATTN + ((size_t)b * 80 + step) * 64 + tid, w, obf);
    }
    __syncthreads();
    // ctx + gate: thread covers f = tid (0..1023); threads < 256 also f = 1024+tid
    const T* fp = feat + (size_t)b * 64 * 1280;
    {
        float c0 = 0.f;
        #pragma unroll 8
        for (int nn = 0; nn < 64; ++nn) c0 += wL[nn] * toF(fp[nn * 1280 + tid]);
        float g = toF(bg_[tid]);
        #pragma unroll
        for (int kp = 0; kp < 4; ++kp) g += gate_part[kp * 40960 + tid * 32 + b];
        g = 1.f / (1.f + expf(-g));
        ctxgT[tid * 32 + b] = c0 * g;
    }
    if (tid < 256) {
        int f = 1024 + tid;
        float c1 = 0.f;
        #pragma unroll 8
        for (int nn = 0; nn < 64; ++nn) c1 += wL[nn] * toF(fp[nn * 1280 + f]);
        float g = toF(bg_[f]);
        #pragma unroll
        for (int kp = 0; kp < 4; ++kp) g += gate_part[kp * 40960 + f * 32 + b];
        g = 1.f / (1.f + expf(-g));
        ctxgT[f * 32 + b] = c1 * g;
    }
}

__global__ __launch_bounds__(1024)
void attn_kernel(const float* hq_part, const float* gate_part, const float* encT,
                 const void* feat, const void* b1, const void* Va, const void* bVa,
                 const void* bg_, float* ctxgT, void* dout, int step,
                 const int* __restrict__ dtf)
{
    int f = *dtf;
    if (f) attn_body<unsigned short>(hq_part, gate_part, encT,
               (const unsigned short*)feat, (const unsigned short*)b1,
               (const unsigned short*)Va, (const unsigned short*)bVa,
               (const unsigned short*)bg_, ctxgT, dout, step, f);
    else   attn_body<float>(hq_part, gate_part, encT,
               (const float*)feat, (const float*)b1, (const float*)Va,
               (const float*)bVa, (const float*)bg_, ctxgT, dout, step, f);
}

// ---- LSTM pointwise: sum 18 partial chunks ----------------------------------
template<typename T>
static __device__ __forceinline__
void lstm_body(const float* __restrict__ gates_part, const T* __restrict__ blstm,
               float* __restrict__ cT, float* __restrict__ actT_h,
               void* __restrict__ dout, int step, int obf)
{
    int g = blockIdx.x * 256 + threadIdx.x;   // 16384 = 512*32
    int b = g & 31, j = g >> 5;
    float gi = toF(blstm[j]),        gf = toF(blstm[j + 512]);
    float gg = toF(blstm[j + 1024]), go = toF(blstm[j + 1536]);
    #pragma unroll
    for (int kc = 0; kc < 18; ++kc) {
        const float* p = gates_part + (size_t)kc * 2048 * 32;
        gi += p[(j       ) * 32 + b];
        gf += p[(j +  512) * 32 + b];
        gg += p[(j + 1024) * 32 + b];
        go += p[(j + 1536) * 32 + b];
    }
    float c  = cT[j * 32 + b];
    float c2 = sigf(gf) * c + sigf(gi) * tanhf(gg);
    float h2 = sigf(go) * tanhf(c2);
    cT[j * 32 + b] = c2;
    actT_h[j * 32 + b] = h2;
    if (step == 79) {
        stw(dout, OFF_H + (size_t)b * 512 + j, h2, obf);
        stw(dout, OFF_C + (size_t)b * 512 + j, c2, obf);
    }
}

__global__ __launch_bounds__(256)
void lstm_pw(const float* gates_part, const void* blstm, float* cT, float* actT_h,
             void* dout, int step, const int* __restrict__ dtf)
{
    int f = *dtf;
    if (f) lstm_body<unsigned short>(gates_part, (const unsigned short*)blstm,
                                     cT, actT_h, dout, step, f);
    else   lstm_body<float>(gates_part, (const float*)blstm, cT, actT_h, dout, step, f);
}

// ---- logits finalize: sum 4 k-partials + bias, store, argmax ----------------
template<typename T>
static __device__ __forceinline__
void logfin_body(const float* __restrict__ part, const T* __restrict__ bout,
                 void* __restrict__ dout, unsigned long long* __restrict__ amax,
                 int step, int obf)
{
    const int mb = blockIdx.x >> 1, bHalf = blockIdx.x & 1;
    const int tid = threadIdx.x, tm = tid & 31, bg = tid >> 5;
    int m0 = mb * 128 + tm * 4;
    if (m0 > 9996) m0 = 9996;                // tail dup (benign)
    const int b0 = bHalf * 16 + bg * 2;

    float l0[4], l1[4];
    #pragma unroll
    for (int i = 0; i < 4; ++i) { float bb = toF(bout[m0 + i]); l0[i] = bb; l1[i] = bb; }
    #pragma unroll
    for (int kc = 0; kc < 4; ++kc) {
        const float* p = part + ((size_t)kc * 10000 + m0) * 32 + b0;
        #pragma unroll
        for (int i = 0; i < 4; ++i) { l0[i] += p[i * 32]; l1[i] += p[i * 32 + 1]; }
    }
    size_t o0 = ((size_t)(b0    ) * 80 + step) * 10000 + m0;
    size_t o1 = ((size_t)(b0 + 1) * 80 + step) * 10000 + m0;
    if (obf) {
        U16x4 s0 = { f2bf(l0[0]), f2bf(l0[1]), f2bf(l0[2]), f2bf(l0[3]) };
        U16x4 s1 = { f2bf(l1[0]), f2bf(l1[1]), f2bf(l1[2]), f2bf(l1[3]) };
        *(U16x4*)((unsigned short*)dout + o0) = s0;
        *(U16x4*)((unsigned short*)dout + o1) = s1;
    } else {
        *(float4*)((float*)dout + o0) = make_float4(l0[0], l0[1], l0[2], l0[3]);
        *(float4*)((float*)dout + o1) = make_float4(l1[0], l1[1], l1[2], l1[3]);
    }
    unsigned long long best0 = packv(l0[0], m0), best1 = packv(l1[0], m0), p;
    #pragma unroll
    for (int i = 1; i < 4; ++i) {
        p = packv(l0[i], m0 + i); if (p > best0) best0 = p;
        p = packv(l1[i], m0 + i); if (p > best1) best1 = p;
    }
    #pragma unroll
    for (int o = 16; o; o >>= 1) {
        unsigned long long v0 = shfl_xor_u64(best0, o);
        unsigned long long v1 = shfl_xor_u64(best1, o);
        if (v0 > best0) best0 = v0;
        if (v1 > best1) best1 = v1;
    }
    if (tm == 0) {
        atomicMax(&amax[step * 32 + b0],     best0);
        atomicMax(&amax[step * 32 + b0 + 1], best1);
    }
}

__global__ __launch_bounds__(256)
void logits_fin(const float* part, const void* bout, void* dout,
                unsigned long long* amax, int step, const int* __restrict__ dtf)
{
    int f = *dtf;
    if (f) logfin_body<unsigned short>(part, (const unsigned short*)bout, dout, amax, step, f);
    else   logfin_body<float>(part, (const float*)bout, dout, amax, step, f);
}

// ---- init kernels (one-time; latency acceptable) ----------------------------
template<typename T>
static __device__ __forceinline__
void mean_body(const T* __restrict__ feat, float* __restrict__ meanT)
{
    int e = blockIdx.x * 256 + threadIdx.x;    // 40960 = 32*1280
    int f = e % 1280, b = e / 1280;
    const T* p = feat + (size_t)b * 64 * 1280 + f;
    float s = 0.f;
    for (int nn = 0; nn < 64; ++nn) s += toF(p[(size_t)nn * 1280]);
    meanT[f * 32 + b] = s * (1.f / 64.f);
}
__global__ __launch_bounds__(256)
void init_mean(const void* feat, float* meanT, const int* __restrict__ dtf)
{
    if (*dtf) mean_body<unsigned short>((const unsigned short*)feat, meanT);
    else      mean_body<float>((const float*)feat, meanT);
}

template<typename T>
static __device__ __forceinline__
void inithc_body(const float* __restrict__ meanT, const T* __restrict__ Wh,
                 const T* __restrict__ bh, const T* __restrict__ Wc,
                 const T* __restrict__ bc, float* __restrict__ actT_h, float* __restrict__ cT)
{
    int mb = blockIdx.x >> 2, bq = blockIdx.x & 3;
    int tid = threadIdx.x, tm = tid & 31;
    int m0 = mb * 128 + tm * 4;
    int b = bq * 8 + (tid >> 5);
    bool isH = (m0 < 512);
    const T* W = isH ? Wh : Wc;
    int mw = isH ? m0 : (m0 - 512);
    float a0=0.f,a1=0.f,a2=0.f,a3=0.f;
    const float* ap = meanT + b;
    const T* wp = W + mw;
    #pragma unroll 8
    for (int k = 0; k < 1280; ++k) {
        float av = *ap;
        F4v w = ld4(wp);
        a0 += w.x * av; a1 += w.y * av; a2 += w.z * av; a3 += w.w * av;
        ap += 32; wp += 512;
    }
    const T* bias = isH ? bh : bc;
    float* dst = isH ? actT_h : cT;
    dst[(mw + 0) * 32 + b] = a0 + toF(bias[mw + 0]);
    dst[(mw + 1) * 32 + b] = a1 + toF(bias[mw + 1]);
    dst[(mw + 2) * 32 + b] = a2 + toF(bias[mw + 2]);
    dst[(mw + 3) * 32 + b] = a3 + toF(bias[mw + 3]);
}
__global__ __launch_bounds__(256)
void init_hc(const float* meanT, const void* Wh, const void* bh, const void* Wc,
             const void* bc, float* actT_h, float* cT, const int* __restrict__ dtf)
{
    if (*dtf) inithc_body<unsigned short>(meanT, (const unsigned short*)Wh,
                  (const unsigned short*)bh, (const unsigned short*)Wc,
                  (const unsigned short*)bc, actT_h, cT);
    else      inithc_body<float>(meanT, (const float*)Wh, (const float*)bh,
                  (const float*)Wc, (const float*)bc, actT_h, cT);
}

// enc_projT[b][j][n] = (feat @ W2 + b2), transposed for coalesced attention reads
template<typename T>
static __device__ __forceinline__
void encproj_body(const T* __restrict__ feat, const T* __restrict__ W2,
                  const T* __restrict__ b2, float* __restrict__ encT)
{
    int jb = blockIdx.x & 3, rowb = blockIdx.x >> 2;
    int tid = threadIdx.x, tm = tid & 31, bg = tid >> 5;
    int j0 = jb * 128 + tm * 4;
    int r0 = rowb * 16 + bg * 2;
    float a00=0.f,a01=0.f,a10=0.f,a11=0.f,a20=0.f,a21=0.f,a30=0.f,a31=0.f;
    const T* f0 = feat + (size_t)r0 * 1280;
    const T* f1 = f0 + 1280;
    const T* wp = W2 + j0;
    #pragma unroll 8
    for (int k = 0; k < 1280; ++k) {
        float ax = toF(f0[k]), ay = toF(f1[k]);
        F4v w = ld4(wp);
        a00 += w.x * ax; a01 += w.x * ay;
        a10 += w.y * ax; a11 += w.y * ay;
        a20 += w.z * ax; a21 += w.z * ay;
        a30 += w.w * ax; a31 += w.w * ay;
        wp += 512;
    }
    int b = r0 >> 6, n = r0 & 63;
    float* base = encT + (size_t)b * 32768 + n;
    float bb;
    bb = toF(b2[j0 + 0]); *(float2*)(base + (size_t)(j0 + 0) * 64) = make_float2(a00 + bb, a01 + bb);
    bb = toF(b2[j0 + 1]); *(float2*)(base + (size_t)(j0 + 1) * 64) = make_float2(a10 + bb, a11 + bb);
    bb = toF(b2[j0 + 2]); *(float2*)(base + (size_t)(j0 + 2) * 64) = make_float2(a20 + bb, a21 + bb);
    bb = toF(b2[j0 + 3]); *(float2*)(base + (size_t)(j0 + 3) * 64) = make_float2(a30 + bb, a31 + bb);
}
__global__ __launch_bounds__(256)
void encproj(const void* feat, const void* W2, const void* b2, float* encT,
             const int* __restrict__ dtf)
{
    if (*dtf) encproj_body<unsigned short>((const unsigned short*)feat,
                  (const unsigned short*)W2, (const unsigned short*)b2, encT);
    else      encproj_body<float>((const float*)feat, (const float*)W2,
                  (const float*)b2, encT);
}

// ---------------------------------------------------------------------------
extern "C" void kernel_launch(void* const* d_in, const int* in_sizes, int n_in,
                              void* d_out, int out_size, void* d_ws, size_t ws_size,
                              hipStream_t stream)
{
    (void)in_sizes; (void)n_in; (void)out_size; (void)ws_size;

    const void* feat  = d_in[0];
    // d_in[1] caption (unused), d_in[2] max_caption (=80, hardcoded)
    const void* emb   = d_in[3];
    const void* W1    = d_in[4];
    const void* b1    = d_in[5];
    const void* W2    = d_in[6];
    const void* b2    = d_in[7];
    const void* Va    = d_in[8];
    const void* bVa   = d_in[9];
    const void* Wh    = d_in[10];
    const void* bh    = d_in[11];
    const void* Wc    = d_in[12];
    const void* bc    = d_in[13];
    const void* Wg    = d_in[14];
    const void* bg    = d_in[15];
    const void* Wx    = d_in[16];
    const void* Whh   = d_in[17];
    const void* blstm = d_in[18];
    const void* Wout  = d_in[19];
    const void* bout  = d_in[20];

    float* ws         = (float*)d_ws;
    float* encT       = ws;                    // 1,048,576
    float* meanT      = encT + 1048576;        // 40,960
    float* actT_h     = meanT + 40960;         // 16,384
    float* cT         = actT_h + 16384;        // 16,384
    float* hq_part    = cT + 16384;            // 4*512*32   = 65,536
    float* gate_part  = hq_part + 65536;       // 4*1280*32  = 163,840
    float* gates_part = gate_part + 163840;    // 18*2048*32 = 1,179,648
    float* ctxgT      = gates_part + 1179648;  // 40,960
    unsigned long long* amax = (unsigned long long*)(ctxgT + 40960);  // 80*32 u64
    int* dtf          = (int*)(amax + 2560);
    // K4 partial buffer (4*10000*32 = 1,280,000 f32) aliases hq/gate/gates
    // partials (1,409,024 f32): time-disjoint within a step (K4 runs after
    // lstm consumed gates; K1 of next step rewrites after fin consumed K4).
    float* k4part     = hq_part;

    detect_init<<<1, 256, 0, stream>>>((const unsigned short*)feat, dtf, amax);
    init_mean<<<160, 256, 0, stream>>>(feat, meanT, dtf);
    init_hc  <<<32, 256, 0, stream>>>(meanT, Wh, bh, Wc, bc, actT_h, cT, dtf);
    encproj  <<<512, 256, 0, stream>>>(feat, W2, b2, encT, dtf);

    // Region: W, W2, actT, part, M, KS, Kc, ldw, mode, nBlocks
    SkArgs k1{};
    k1.r[0] = { W1,  nullptr, actT_h, hq_part,    512, 4, 128,  512, 0,  32 };
    k1.r[1] = { Wg,  nullptr, actT_h, gate_part, 1280, 4, 128, 1280, 0,  80 };
    k1.r[2] = { Whh, Wx,      actT_h, gates_part,2048, 8, 128, 2048, 1, 256 };
    k1.nReg = 3;
    SkArgs k3{};
    k3.r[0] = { Wx, nullptr, ctxgT,
                gates_part + (size_t)8 * 2048 * 32, 2048, 10, 128, 2048, 3, 320 };
    k3.nReg = 1;
    SkArgs k4{};
    k4.r[0] = { Wout, nullptr, actT_h, k4part, 10000, 4, 128, 10000, 0, 632 };
    k4.nReg = 1;

    for (int t = 0; t < 80; ++t) {
        skgemm     <<<368, 256,  0, stream>>>(k1, t, amax, emb, dtf);
        attn_kernel<<<32,  1024, 0, stream>>>(hq_part, gate_part, encT, feat,
                                              b1, Va, bVa, bg, ctxgT, d_out, t, dtf);
        skgemm     <<<320, 256,  0, stream>>>(k3, t, amax, emb, dtf);
        lstm_pw    <<<64,  256,  0, stream>>>(gates_part, blstm, cT, actT_h, d_out, t, dtf);
        skgemm     <<<632, 256,  0, stream>>>(k4, t, amax, emb, dtf);
        logits_fin <<<158, 256,  0, stream>>>(k4part, bout, d_out, amax, t, dtf);
    }
}